// Round 3
// baseline (4497.839 us; speedup 1.0000x reference)
//
#include <hip/hip_runtime.h>
#include <cstdint>
#include <cstddef>

// ============================================================================
// EFLSTM: concat(x_text,x_audio,x_vision) -> LSTM(H=1024, T=256, B=256) -> MLP
//
// Round 11 = R10 with the fused xg GEMM software-pipelined ONE FULL STEP deep.
//  - R10 post-mortem: VGPR_Count stayed 152 -> compiler sank the 52 xb loads
//    back to their MFMA uses (same straight-line region), recreating ~5
//    serialized LLC windows per step (11.8us/step).
//  - R11: loads issued in iter ts are consumed in iter ts+1. Cross-backedge
//    liveness FORCES the Axb[4][13] buffer into registers (expect ~390 VGPR),
//    and gives each load burst a full step (~6us) of slack -> latency hidden
//    regardless of scheduler choices. Pipeline:
//      prologue: xacc(0) computed directly; Axb <- xb frags of step 1
//      iter ts : ... flag release
//                -> xacc(ts+1) = bias + sum_k Axb*Bih   (pure register MFMA)
//                -> if ts<254: Axb <- xb frags of step ts+2 (fire-and-forget)
//                -> poll
//  - Everything else (persistent single-launch scan, S1/S3/S4 fence-free
//    protocol, in-register c, xg never touching memory) identical to R10.
// LDS: A 128 KB + gl 17 KB = 148480 B. 1 block/CU.
// ============================================================================

typedef __attribute__((ext_vector_type(8))) short short8;   // 8 x bf16
typedef __attribute__((ext_vector_type(4))) float f32x4;

#define MFMA_BF16(A,B,C) __builtin_amdgcn_mfma_f32_16x16x32_bf16((A),(B),(C),0,0,0)

// ---- workspace layout (bytes) ----
#define OFF_FLAGS 0u            // 256 * 4 (padded to 4096)
#define OFF_HBUF0 4096u         // 256*1024*2 = 524288   (A-frag-linear bf16)
#define ZERO_SPAN 528384u       // flags + hbuf0 zeroed every launch
#define OFF_HBUF1 528384u       // 524288
#define OFF_HFIN  1052672u      // 256*1024*4 = 1048576  (fp32 h_last)
#define OFF_HID   2101248u      // 256*512*4  = 524288   (fp32 mlp hidden)
#define OFF_BIAS  2625536u      // 4096*4 (padded to 16384)
#define OFF_WHH   2641920u      // 64 slices * 64*1024 * 2 = 8388608
#define OFF_WIH   11030528u     // 256*13*64*8*2 = 3407872
#define OFF_XB    14438400u     // 4096*13*64*8*2 = 54525952
#define WS_NEED   68964352ull

static __device__ __forceinline__ uint16_t f2bf(float f) {
  uint32_t u = __builtin_bit_cast(uint32_t, f);
  uint32_t r = u + 0x7FFFu + ((u >> 16) & 1u);   // round-nearest-even
  return (uint16_t)(r >> 16);
}
static __device__ __forceinline__ float sigm(float x) {
  return 1.0f / (1.0f + __expf(-x));
}
static __device__ __forceinline__ float tanh_f(float x) {
  float e = __expf(2.0f * x);
  return 1.0f - 2.0f / (e + 1.0f);
}
// async global->LDS, 16B/lane, aux=0x11 (SC0|SC1): IF-coherent read,
// bypasses the non-coherent per-XCD L2.
static __device__ __forceinline__ void gld_lds16_coh(const void* gsrc, void* ldst) {
  __builtin_amdgcn_global_load_lds(
      (const __attribute__((address_space(1))) uint32_t*)gsrc,
      (__attribute__((address_space(3))) uint32_t*)ldst, 16, 0, 0x11);
}

// ---------------------------------------------------------------------------
// pack x (3 tensors, fp32 [B,T,D_i]) -> xb bf16 A-frag-linear:
//   [mtile 4096][ks 13][lane 64][8], m = t*256+b, k padded to 416 with zeros
// ---------------------------------------------------------------------------
__global__ __launch_bounds__(256) void pack_xb_kernel(
    const float* __restrict__ xt, const float* __restrict__ xa,
    const float* __restrict__ xv, uint16_t* __restrict__ xb)
{
  int id = blockIdx.x * 256 + threadIdx.x;          // < 4096*13*64 = 3407872
  int lane = id & 63;
  int rem  = id >> 6;
  int ks = rem % 13;
  int mt = rem / 13;
  int m = mt * 16 + (lane & 15);
  int t = m >> 8;
  int b = m & 255;
  int k0 = ks * 32 + (lane >> 4) * 8;
  size_t base = (size_t)b * 256 + t;
  uint16_t vals[8];
#pragma unroll
  for (int e = 0; e < 8; ++e) {
    int k = k0 + e;
    float v;
    if (k < 300)      v = xt[base * 300 + k];
    else if (k < 374) v = xa[base * 74  + (k - 300)];
    else if (k < 409) v = xv[base * 35  + (k - 374)];
    else              v = 0.0f;
    vals[e] = f2bf(v);
  }
  uint32_t* d32 = (uint32_t*)(xb + (size_t)id * 8);
#pragma unroll
  for (int i = 0; i < 4; ++i)
    d32[i] = (uint32_t)vals[2*i] | ((uint32_t)vals[2*i+1] << 16);
}

// ---------------------------------------------------------------------------
// pack W_hh fp32 [4096,1024] -> bf16 B-frag-linear per scan block s:
//   [s 64][q 4][ks 32][lane 64][8], row = q*1024 + 16*s + (lane&15)
// ---------------------------------------------------------------------------
__global__ __launch_bounds__(256) void pack_whh_kernel(
    const float* __restrict__ whh, uint16_t* __restrict__ wp)
{
  int id = blockIdx.x * 256 + threadIdx.x;          // < 64*4*32*64 = 524288
  int lane = id & 63;
  int ks = (id >> 6) & 31;
  int q  = (id >> 11) & 3;
  int s  = id >> 13;
  int row = q * 1024 + s * 16 + (lane & 15);
  int k0 = ks * 32 + (lane >> 4) * 8;
  const float* src = whh + (size_t)row * 1024 + k0;
  uint16_t vals[8];
#pragma unroll
  for (int e = 0; e < 8; ++e) vals[e] = f2bf(src[e]);
  uint32_t* d32 = (uint32_t*)(wp + (size_t)id * 8);
#pragma unroll
  for (int i = 0; i < 4; ++i)
    d32[i] = (uint32_t)vals[2*i] | ((uint32_t)vals[2*i+1] << 16);
}

// ---------------------------------------------------------------------------
// pack W_ih fp32 [4096,409] -> bf16 B-frag-linear [nt 256][ks 13][lane][8]
// ---------------------------------------------------------------------------
__global__ __launch_bounds__(256) void pack_wih_kernel(
    const float* __restrict__ wih, uint16_t* __restrict__ wp)
{
  int id = blockIdx.x * 256 + threadIdx.x;          // < 256*13*64 = 212992
  int lane = id & 63;
  int rem = id >> 6;
  int ks = rem % 13;
  int nt = rem / 13;
  int n = nt * 16 + (lane & 15);
  int k0 = ks * 32 + (lane >> 4) * 8;
  uint16_t vals[8];
#pragma unroll
  for (int e = 0; e < 8; ++e) {
    int k = k0 + e;
    vals[e] = (k < 409) ? f2bf(wih[(size_t)n * 409 + k]) : (uint16_t)0;
  }
  uint32_t* d32 = (uint32_t*)(wp + (size_t)id * 8);
#pragma unroll
  for (int i = 0; i < 4; ++i)
    d32[i] = (uint32_t)vals[2*i] | ((uint32_t)vals[2*i+1] << 16);
}

__global__ __launch_bounds__(256) void pack_bias_kernel(
    const float* __restrict__ b_ih, const float* __restrict__ b_hh,
    float* __restrict__ bias)
{
  int id = blockIdx.x * 256 + threadIdx.x;          // < 4096
  bias[id] = b_ih[id] + b_hh[id];
}

// ---------------------------------------------------------------------------
// Persistent scan: 256 blocks x 256 threads, 1 block/CU, ONE launch for all
// 256 timesteps. group g = bid>>6 owns batch rows [64g,64g+64); slice
// s = bid&63 owns hidden units [16s,16s+16). Wave w <-> gate quadrant w.
// Per step:
//   issue 128 gld_lds (A h-tile, 128 KB, 32/wave) -> acc init from in-reg xg
//   -> S1 (vmcnt drain, R6 lesson) -> K loop (4 ds_read_b128 A + 1 W L2 load
//   + 4 MFMA per ks) -> gl write -> S3 -> in-thread elementwise (c f32x4)
//   -> contiguous 8B h' agent store -> S4 -> flag release
//   -> xacc(ts+1) = bias + sum Axb*Bih   (Axb loaded LAST iter: pure reg)
//   -> refill Axb with step ts+2's xb frags (consumed next iter)
//   -> all-lane poll.
// xg never touches memory; groups are independent; flags are monotonic.
// ---------------------------------------------------------------------------
__global__ __launch_bounds__(256, 1) void scan_kernel(
    const uint16_t* __restrict__ whh_p, const short8* __restrict__ xb,
    const short8* __restrict__ wih, const float* __restrict__ bias,
    uint16_t* __restrict__ hbuf0, uint16_t* __restrict__ hbuf1,
    float* __restrict__ h_final, uint32_t* flags)
{
  extern __shared__ char smem[];
  // smem[0      .. 131072): A tile, 4 mtiles x 32 ks x 64 lanes x 16 B
  // smem[131072 .. 148480): gate exchange, [64][68] fp32
  float* gl = (float*)(smem + 131072);

  const int tid = threadIdx.x;
  const int bid = blockIdx.x;
  const int g = bid >> 6, s = bid & 63;
  const int lane = tid & 63, w = tid >> 6;   // w = gate quadrant

  // wave-private W_hh stream: quadrant w, frag at ks -> wstream[ks*64]
  const short8* wstream = (const short8*)(whh_p + (size_t)s * 65536)
                          + ((size_t)w * 32) * 64 + lane;

  // elementwise ownership: thread handles units col_e..col_e+3 of row R_e
  const int row_e = tid >> 2;                // 0..63
  const int j_e = (tid & 3) * 4;             // 0,4,8,12
  const int R_e = g * 64 + row_e;
  const int col_e = s * 16 + j_e;            // hidden col base
  f32x4 c4 = {0.0f, 0.0f, 0.0f, 0.0f};       // cell state lives in regs

  // precompute h'-store address (4 consecutive bf16 = one aligned 8B store)
  size_t hstore_base;
  {
    int cg0 = col_e;
    int ksh = cg0 >> 5, quad = (cg0 >> 3) & 3, e0 = cg0 & 7;
    int mth = row_e >> 4;
    int laneh = quad * 16 + (row_e & 15);
    hstore_base = (((size_t)(g * 4 + mth) * 32 + ksh) * 64 + laneh) * 8 + e0;
  }

  const short8* Afrag = (const short8*)smem;
  const int myflag = g * 64 + lane;

  // ---- persistent W_ih B-frags + bias for this wave's gate tile nt ----
  const int nt = w * 64 + s;                 // global ntile 0..255
  short8 Bih[13];
  {
    const short8* bsrc = wih + ((size_t)nt * 13) * 64 + lane;
#pragma unroll
    for (int ks = 0; ks < 13; ++ks) Bih[ks] = bsrc[ks * 64];
  }
  const float bv = bias[nt * 16 + (lane & 15)];

  // ---- prologue: xacc(0) computed directly; Axb <- xb frags of step 1 ----
  f32x4 xacc[4];
  short8 Axb[4][13];                         // loop-carried: step ts+1's frags
  {
    const short8* ab0 = xb + (((size_t)g * 4) * 13) * 64 + lane;
    short8 t0[4][13];
#pragma unroll
    for (int kk = 0; kk < 13; ++kk)
#pragma unroll
      for (int a = 0; a < 4; ++a)
        t0[a][kk] = ab0[((size_t)a * 13 + kk) * 64];
#pragma unroll
    for (int a = 0; a < 4; ++a) { f32x4 v = {bv, bv, bv, bv}; xacc[a] = v; }
#pragma unroll
    for (int kk = 0; kk < 13; ++kk)
#pragma unroll
      for (int a = 0; a < 4; ++a)
        xacc[a] = MFMA_BF16(t0[a][kk], Bih[kk], xacc[a]);

    const short8* ab1 = xb + (((size_t)16 + g * 4) * 13) * 64 + lane;
#pragma unroll
    for (int kk = 0; kk < 13; ++kk)
#pragma unroll
      for (int a = 0; a < 4; ++a)
        Axb[a][kk] = ab1[((size_t)a * 13 + kk) * 64];
  }

#pragma unroll 1
  for (int ts = 0; ts < 256; ++ts) {
    const uint16_t* hin = (ts & 1) ? hbuf1 : hbuf0;
    uint16_t* hout = (ts & 1) ? hbuf0 : hbuf1;

    // ---- stage this step's A h-tile into LDS: 128 x (1 KB), 32 per wave ----
    {
      const uint16_t* gbase = hin + (size_t)g * 65536
                              + (size_t)(w * 32) * 512 + (size_t)lane * 8;
      char* lbase = smem + (size_t)(w * 32) * 1024;
#pragma unroll
      for (int p = 0; p < 32; ++p)
        gld_lds16_coh(gbase + (size_t)p * 512, lbase + p * 1024);
    }

    // acc init from the in-register pipelined xg (f32, no bf16 round-trip)
    f32x4 acc[4];
#pragma unroll
    for (int a = 0; a < 4; ++a) acc[a] = xacc[a];

    __syncthreads();   // S1: vmcnt(0) drain — async LDS writes are NOT
                       // auto-ordered before ds_read (R6 NaN lesson)

    // ---- K loop: one W L2 stream, 4 A ds_reads, 4 MFMA per ks ----
#pragma unroll
    for (int ks = 0; ks < 32; ++ks) {
      short8 W = wstream[ks * 64];
      short8 A0 = Afrag[(0 * 32 + ks) * 64 + lane];
      short8 A1 = Afrag[(1 * 32 + ks) * 64 + lane];
      short8 A2 = Afrag[(2 * 32 + ks) * 64 + lane];
      short8 A3 = Afrag[(3 * 32 + ks) * 64 + lane];
      acc[0] = MFMA_BF16(A0, W, acc[0]);
      acc[1] = MFMA_BF16(A1, W, acc[1]);
      acc[2] = MFMA_BF16(A2, W, acc[2]);
      acc[3] = MFMA_BF16(A3, W, acc[3]);
    }

    // gates -> LDS  (C layout: col=lane&15, row=(lane>>4)*4+reg)
    {
      int r0 = (lane >> 4) * 4;
      int cc = lane & 15;
      int colc = w * 16 + cc;
#pragma unroll
      for (int a = 0; a < 4; ++a)
#pragma unroll
        for (int r = 0; r < 4; ++r)
          gl[(a * 16 + r0 + r) * 68 + colc] = acc[a][r];
    }
    __syncthreads();   // S3: gates visible (A-tile reads also complete)

    // LSTM elementwise (PyTorch gate order i,f,g,o)
    float hv[4];
#pragma unroll
    for (int u = 0; u < 4; ++u) {
      int cj = j_e + u;
      float xi = gl[row_e * 68 + cj];
      float xf = gl[row_e * 68 + 16 + cj];
      float xg_ = gl[row_e * 68 + 32 + cj];
      float xo = gl[row_e * 68 + 48 + cj];
      float cn = sigm(xf) * c4[u] + sigm(xi) * tanh_f(xg_);
      c4[u] = cn;
      hv[u] = sigm(xo) * tanh_f(cn);
    }
    // h' as ONE contiguous 8-byte agent-scope store per thread
    {
      uint32_t w0 = (uint32_t)f2bf(hv[0]) | ((uint32_t)f2bf(hv[1]) << 16);
      uint32_t w1 = (uint32_t)f2bf(hv[2]) | ((uint32_t)f2bf(hv[3]) << 16);
      unsigned long long v = ((unsigned long long)w1 << 32) | w0;
      __hip_atomic_store((unsigned long long*)(hout + hstore_base), v,
                         __ATOMIC_RELAXED, __HIP_MEMORY_SCOPE_AGENT);
    }
    if (ts == 255) {
      f32x4 hh = {hv[0], hv[1], hv[2], hv[3]};
      *(f32x4*)(h_final + (size_t)R_e * 1024 + col_e) = hh;
    } else {
      // ---- group-local barrier (64 blocks of group g), fence-free ----
      __syncthreads();   // S4: drains every wave's h' stores
      if (tid == 0) {
        __hip_atomic_store(&flags[bid], (uint32_t)(ts + 1),
                           __ATOMIC_RELAXED, __HIP_MEMORY_SCOPE_AGENT);
      }
      // xacc(ts+1) from Axb loaded LAST iteration: pure register MFMA,
      // zero memory wait (the loads have had a full ~6us step to land).
#pragma unroll
      for (int a = 0; a < 4; ++a) { f32x4 v = {bv, bv, bv, bv}; xacc[a] = v; }
#pragma unroll
      for (int kk = 0; kk < 13; ++kk)
#pragma unroll
        for (int a = 0; a < 4; ++a)
          xacc[a] = MFMA_BF16(Axb[a][kk], Bih[kk], xacc[a]);
      // refill Axb with step ts+2's frags (fire-and-forget; consumed next
      // iter -> cross-backedge liveness forces register residency)
      if (ts < 254) {
        const short8* abase =
            xb + (((size_t)(ts + 2) * 16 + g * 4) * 13) * 64 + lane;
#pragma unroll
        for (int kk = 0; kk < 13; ++kk)
#pragma unroll
          for (int a = 0; a < 4; ++a)
            Axb[a][kk] = abase[((size_t)a * 13 + kk) * 64];
      }
      // all lanes poll one peer flag each; wave proceeds when all 64 peers
      // released. No S5: staging only overwrites the A region (reads fenced
      // by S4); gl(l+1) writes are fenced by S1(l+1).
      while (__hip_atomic_load(&flags[myflag], __ATOMIC_RELAXED,
                               __HIP_MEMORY_SCOPE_AGENT) < (uint32_t)(ts + 1)) {
        __builtin_amdgcn_s_sleep(1);
      }
    }
  }
}

// ---------------------------------------------------------------------------
// MLP layer 1: hidden = relu(h_last @ W1^T + b1), fp32 VALU.
// ---------------------------------------------------------------------------
__global__ __launch_bounds__(256) void mlp1_kernel(
    const float* __restrict__ h_final, const float* __restrict__ W1,
    const float* __restrict__ b1, float* __restrict__ hidden)
{
  __shared__ float hl[8 * 1024];       // 32 KB
  __shared__ float part[4 * 64 * 8];   // 8 KB
  int tid = threadIdx.x;
  int rb = blockIdx.x;                 // 0..31
  int cb = blockIdx.y;                 // 0..7
  const f32x4* hsrc = (const f32x4*)(h_final + (size_t)rb * 8 * 1024);
  for (int i = tid; i < 2048; i += 256) ((f32x4*)hl)[i] = hsrc[i];
  __syncthreads();
  int cell_l = tid & 63;
  int kq = tid >> 6;                   // k quarter
  int cell = cb * 64 + cell_l;
  float accv[8] = {0,0,0,0,0,0,0,0};
  const f32x4* wrow = (const f32x4*)(W1 + (size_t)cell * 1024) + kq * 64;
  const f32x4* hl4 = (const f32x4*)hl;
  for (int k4 = 0; k4 < 64; ++k4) {
    f32x4 wv = wrow[k4];
    int kidx = kq * 64 + k4;
#pragma unroll
    for (int r = 0; r < 8; ++r) {
      f32x4 hv = hl4[r * 256 + kidx];
      accv[r] += wv[0] * hv[0] + wv[1] * hv[1] + wv[2] * hv[2] + wv[3] * hv[3];
    }
  }
#pragma unroll
  for (int r = 0; r < 8; ++r) part[(kq * 64 + cell_l) * 8 + r] = accv[r];
  __syncthreads();
#pragma unroll
  for (int rr = 0; rr < 2; ++rr) {
    int r = kq * 2 + rr;
    float sum = b1[cell];
    for (int q = 0; q < 4; ++q) sum += part[(q * 64 + cell_l) * 8 + r];
    hidden[(size_t)(rb * 8 + r) * 512 + cell] = fmaxf(sum, 0.0f);
  }
}

// MLP layer 2: out[b] = hidden[b] . W2 + b2
__global__ __launch_bounds__(256) void mlp2_kernel(
    const float* __restrict__ hidden, const float* __restrict__ W2,
    const float* __restrict__ b2, float* __restrict__ out)
{
  __shared__ float w2l[512];
  int tid = threadIdx.x;
  for (int i = tid; i < 512; i += 256) w2l[i] = W2[i];
  __syncthreads();
  const f32x4* hrow = (const f32x4*)(hidden + (size_t)tid * 512);
  const f32x4* w4 = (const f32x4*)w2l;
  float acc = b2[0];
  for (int k = 0; k < 128; ++k) {
    f32x4 a = hrow[k], b = w4[k];
    acc += a[0] * b[0] + a[1] * b[1] + a[2] * b[2] + a[3] * b[3];
  }
  out[tid] = acc;
}

// ---------------------------------------------------------------------------
extern "C" void kernel_launch(void* const* d_in, const int* in_sizes, int n_in,
                              void* d_out, int out_size, void* d_ws, size_t ws_size,
                              hipStream_t stream)
{
  (void)in_sizes; (void)n_in; (void)out_size;
  if (ws_size < WS_NEED) return;   // workspace too small -> loud bench failure

  const float* xt   = (const float*)d_in[0];
  const float* xa   = (const float*)d_in[1];
  const float* xv   = (const float*)d_in[2];
  const float* W_ih = (const float*)d_in[3];
  const float* W_hh = (const float*)d_in[4];
  const float* b_ih = (const float*)d_in[5];
  const float* b_hh = (const float*)d_in[6];
  const float* W1   = (const float*)d_in[7];
  const float* b1   = (const float*)d_in[8];
  const float* W2   = (const float*)d_in[9];
  const float* b2   = (const float*)d_in[10];
  float* out = (float*)d_out;
  char* ws = (char*)d_ws;

  uint32_t* flags   = (uint32_t*)(ws + OFF_FLAGS);
  uint16_t* hb0     = (uint16_t*)(ws + OFF_HBUF0);
  uint16_t* hb1     = (uint16_t*)(ws + OFF_HBUF1);
  float*    h_final = (float*)(ws + OFF_HFIN);
  float*    hidden  = (float*)(ws + OFF_HID);
  float*    bias    = (float*)(ws + OFF_BIAS);
  uint16_t* whh_p   = (uint16_t*)(ws + OFF_WHH);
  uint16_t* wih_p   = (uint16_t*)(ws + OFF_WIH);
  uint16_t* xb      = (uint16_t*)(ws + OFF_XB);

  // allow >64KB dynamic LDS for the scan kernel (idempotent, capture-safe)
  hipFuncSetAttribute((const void*)scan_kernel,
                      hipFuncAttributeMaxDynamicSharedMemorySize, 148480);

  // zero flags + h state (ws is poisoned before every launch)
  hipMemsetAsync(ws, 0, ZERO_SPAN, stream);

  pack_xb_kernel  <<<13312, 256, 0, stream>>>(xt, xa, xv, xb);
  pack_whh_kernel <<<2048,  256, 0, stream>>>(W_hh, whh_p);
  pack_wih_kernel <<<832,   256, 0, stream>>>(W_ih, wih_p);
  pack_bias_kernel<<<16,    256, 0, stream>>>(b_ih, b_hh, bias);

  scan_kernel<<<256, 256, 148480, stream>>>(
      whh_p, (const short8*)xb, (const short8*)wih_p, bias,
      hb0, hb1, h_final, flags);

  mlp1_kernel<<<dim3(32, 8), 256, 0, stream>>>(h_final, W1, b1, hidden);
  mlp2_kernel<<<1, 256, 0, stream>>>(hidden, W2, b2, out);
}

// Round 5
// 1910.318 us; speedup vs baseline: 2.3545x; 2.3545x over previous
//
#include <hip/hip_runtime.h>
#include <cstdint>
#include <cstddef>

// ============================================================================
// EFLSTM: concat(x_text,x_audio,x_vision) -> LSTM(H=1024, T=256, B=256) -> MLP
//
// Round 13 = R12 resubmitted verbatim (R12 hit a GPU-acquisition timeout and
// never ran). R8's PROVEN step skeleton + persistent single-launch scan +
// fused xg staged through LDS (not VGPRs).
//  - R9/R10/R11 post-mortems: any fused-xg holding 52 A-frags in VGPRs fails
//    (vmcnt serialization / scheduler sinking / 256-VGPR ceiling + 5.8 GB
//    refetch). Bulk xg operands must NOT be register-resident.
//  - R12: the A-region (128 KB LDS) is dead between S3 and the next step's
//    A-staging. Per step: after S3 issue 13 gld_lds/wave pulling step ts+1's
//    52 KB xb slice into A-region bytes [0,52K) (async, zero VGPR); S4's
//    vmcnt drain completes it under the elementwise phase; after the flag
//    release each wave does 52 ds_read_b128 + 52 MFMA -> xacc (16 loop-
//    carried VGPRs) inside the idle poll window; S5 (re-added) fences xb
//    reads against the next A-staging overwrite.
//  - Persistent Bih[13] (52 VGPR) + bias in regs; c in regs; xg never
//    touches memory; 8 xg_gemm launches + 7 scan boundaries stay deleted.
//  - Step protocol: S1 (post-A-stage vmcnt drain, R6 NaN lesson), S3 (gates
//    visible), S4 (h' + xb-stage drain), S5 (xb-read fence) -> poll.
// LDS: A 128 KB + gl 17 KB = 148480 B. 1 block/CU.
// ============================================================================

typedef __attribute__((ext_vector_type(8))) short short8;   // 8 x bf16
typedef __attribute__((ext_vector_type(4))) float f32x4;

#define MFMA_BF16(A,B,C) __builtin_amdgcn_mfma_f32_16x16x32_bf16((A),(B),(C),0,0,0)

// ---- workspace layout (bytes) ----
#define OFF_FLAGS 0u            // 256 * 4 (padded to 4096)
#define OFF_HBUF0 4096u         // 256*1024*2 = 524288   (A-frag-linear bf16)
#define ZERO_SPAN 528384u       // flags + hbuf0 zeroed every launch
#define OFF_HBUF1 528384u       // 524288
#define OFF_HFIN  1052672u      // 256*1024*4 = 1048576  (fp32 h_last)
#define OFF_HID   2101248u      // 256*512*4  = 524288   (fp32 mlp hidden)
#define OFF_BIAS  2625536u      // 4096*4 (padded to 16384)
#define OFF_WHH   2641920u      // 64 slices * 64*1024 * 2 = 8388608
#define OFF_WIH   11030528u     // 256*13*64*8*2 = 3407872
#define OFF_XB    14438400u     // 4096*13*64*8*2 = 54525952
#define WS_NEED   68964352ull

static __device__ __forceinline__ uint16_t f2bf(float f) {
  uint32_t u = __builtin_bit_cast(uint32_t, f);
  uint32_t r = u + 0x7FFFu + ((u >> 16) & 1u);   // round-nearest-even
  return (uint16_t)(r >> 16);
}
static __device__ __forceinline__ float sigm(float x) {
  return 1.0f / (1.0f + __expf(-x));
}
static __device__ __forceinline__ float tanh_f(float x) {
  float e = __expf(2.0f * x);
  return 1.0f - 2.0f / (e + 1.0f);
}
// async global->LDS, 16B/lane, aux=0x11 (SC0|SC1): IF-coherent read,
// bypasses the non-coherent per-XCD L2.
static __device__ __forceinline__ void gld_lds16_coh(const void* gsrc, void* ldst) {
  __builtin_amdgcn_global_load_lds(
      (const __attribute__((address_space(1))) uint32_t*)gsrc,
      (__attribute__((address_space(3))) uint32_t*)ldst, 16, 0, 0x11);
}
// async global->LDS, 16B/lane, aux=0 (normal cached read: xb is read-only,
// producer finished before scan launch -> no coherence needed, L2 may serve)
static __device__ __forceinline__ void gld_lds16(const void* gsrc, void* ldst) {
  __builtin_amdgcn_global_load_lds(
      (const __attribute__((address_space(1))) uint32_t*)gsrc,
      (__attribute__((address_space(3))) uint32_t*)ldst, 16, 0, 0);
}

// ---------------------------------------------------------------------------
// pack x (3 tensors, fp32 [B,T,D_i]) -> xb bf16 A-frag-linear:
//   [mtile 4096][ks 13][lane 64][8], m = t*256+b, k padded to 416 with zeros
// ---------------------------------------------------------------------------
__global__ __launch_bounds__(256) void pack_xb_kernel(
    const float* __restrict__ xt, const float* __restrict__ xa,
    const float* __restrict__ xv, uint16_t* __restrict__ xb)
{
  int id = blockIdx.x * 256 + threadIdx.x;          // < 4096*13*64 = 3407872
  int lane = id & 63;
  int rem  = id >> 6;
  int ks = rem % 13;
  int mt = rem / 13;
  int m = mt * 16 + (lane & 15);
  int t = m >> 8;
  int b = m & 255;
  int k0 = ks * 32 + (lane >> 4) * 8;
  size_t base = (size_t)b * 256 + t;
  uint16_t vals[8];
#pragma unroll
  for (int e = 0; e < 8; ++e) {
    int k = k0 + e;
    float v;
    if (k < 300)      v = xt[base * 300 + k];
    else if (k < 374) v = xa[base * 74  + (k - 300)];
    else if (k < 409) v = xv[base * 35  + (k - 374)];
    else              v = 0.0f;
    vals[e] = f2bf(v);
  }
  uint32_t* d32 = (uint32_t*)(xb + (size_t)id * 8);
#pragma unroll
  for (int i = 0; i < 4; ++i)
    d32[i] = (uint32_t)vals[2*i] | ((uint32_t)vals[2*i+1] << 16);
}

// ---------------------------------------------------------------------------
// pack W_hh fp32 [4096,1024] -> bf16 B-frag-linear per scan block s:
//   [s 64][q 4][ks 32][lane 64][8], row = q*1024 + 16*s + (lane&15)
// ---------------------------------------------------------------------------
__global__ __launch_bounds__(256) void pack_whh_kernel(
    const float* __restrict__ whh, uint16_t* __restrict__ wp)
{
  int id = blockIdx.x * 256 + threadIdx.x;          // < 64*4*32*64 = 524288
  int lane = id & 63;
  int ks = (id >> 6) & 31;
  int q  = (id >> 11) & 3;
  int s  = id >> 13;
  int row = q * 1024 + s * 16 + (lane & 15);
  int k0 = ks * 32 + (lane >> 4) * 8;
  const float* src = whh + (size_t)row * 1024 + k0;
  uint16_t vals[8];
#pragma unroll
  for (int e = 0; e < 8; ++e) vals[e] = f2bf(src[e]);
  uint32_t* d32 = (uint32_t*)(wp + (size_t)id * 8);
#pragma unroll
  for (int i = 0; i < 4; ++i)
    d32[i] = (uint32_t)vals[2*i] | ((uint32_t)vals[2*i+1] << 16);
}

// ---------------------------------------------------------------------------
// pack W_ih fp32 [4096,409] -> bf16 B-frag-linear [nt 256][ks 13][lane][8]
// ---------------------------------------------------------------------------
__global__ __launch_bounds__(256) void pack_wih_kernel(
    const float* __restrict__ wih, uint16_t* __restrict__ wp)
{
  int id = blockIdx.x * 256 + threadIdx.x;          // < 256*13*64 = 212992
  int lane = id & 63;
  int rem = id >> 6;
  int ks = rem % 13;
  int nt = rem / 13;
  int n = nt * 16 + (lane & 15);
  int k0 = ks * 32 + (lane >> 4) * 8;
  uint16_t vals[8];
#pragma unroll
  for (int e = 0; e < 8; ++e) {
    int k = k0 + e;
    vals[e] = (k < 409) ? f2bf(wih[(size_t)n * 409 + k]) : (uint16_t)0;
  }
  uint32_t* d32 = (uint32_t*)(wp + (size_t)id * 8);
#pragma unroll
  for (int i = 0; i < 4; ++i)
    d32[i] = (uint32_t)vals[2*i] | ((uint32_t)vals[2*i+1] << 16);
}

__global__ __launch_bounds__(256) void pack_bias_kernel(
    const float* __restrict__ b_ih, const float* __restrict__ b_hh,
    float* __restrict__ bias)
{
  int id = blockIdx.x * 256 + threadIdx.x;          // < 4096
  bias[id] = b_ih[id] + b_hh[id];
}

// ---------------------------------------------------------------------------
// Persistent scan: 256 blocks x 256 threads, 1 block/CU, ONE launch for all
// 256 timesteps. group g = bid>>6 owns batch rows [64g,64g+64); slice
// s = bid&63 owns hidden units [16s,16s+16). Wave w <-> gate quadrant w.
// Per step:
//   issue 128 gld_lds (A h-tile, 128 KB, 32/wave) -> acc init from in-reg xg
//   -> S1 (vmcnt drain, R6 lesson) -> K loop (4 A ds_reads + 1 W L2 load
//   + 4 MFMA per ks) -> gl write -> S3 -> issue 13 gld_lds/wave (xb slice of
//   step ts+1 into A-region[0,52K), async, zero VGPR) -> in-thread
//   elementwise (c f32x4) -> contiguous 8B h' agent store -> S4 (drains h'
//   AND the xb stage) -> flag release -> xg-MFMA for ts+1 (52 ds_read_b128 +
//   52 MFMA -> xacc, in the idle poll window) -> S5 (fence xb reads vs next
//   A-staging) -> all-lane poll.
// xg never touches memory; groups are independent; flags are monotonic.
// ---------------------------------------------------------------------------
__global__ __launch_bounds__(256, 1) void scan_kernel(
    const uint16_t* __restrict__ whh_p, const short8* __restrict__ xb,
    const short8* __restrict__ wih, const float* __restrict__ bias,
    uint16_t* __restrict__ hbuf0, uint16_t* __restrict__ hbuf1,
    float* __restrict__ h_final, uint32_t* flags)
{
  extern __shared__ char smem[];
  // smem[0      .. 131072): A tile, 4 mtiles x 32 ks x 64 lanes x 16 B
  //                         (doubles as xb staging [0,53248) in wait window)
  // smem[131072 .. 148480): gate exchange, [64][68] fp32
  float* gl = (float*)(smem + 131072);

  const int tid = threadIdx.x;
  const int bid = blockIdx.x;
  const int g = bid >> 6, s = bid & 63;
  const int lane = tid & 63, w = tid >> 6;   // w = gate quadrant

  // wave-private W_hh stream: quadrant w, frag at ks -> wstream[ks*64]
  const short8* wstream = (const short8*)(whh_p + (size_t)s * 65536)
                          + ((size_t)w * 32) * 64 + lane;

  // elementwise ownership: thread handles units col_e..col_e+3 of row R_e
  const int row_e = tid >> 2;                // 0..63
  const int j_e = (tid & 3) * 4;             // 0,4,8,12
  const int R_e = g * 64 + row_e;
  const int col_e = s * 16 + j_e;            // hidden col base
  f32x4 c4 = {0.0f, 0.0f, 0.0f, 0.0f};       // cell state lives in regs

  // precompute h'-store address (4 consecutive bf16 = one aligned 8B store)
  size_t hstore_base;
  {
    int cg0 = col_e;
    int ksh = cg0 >> 5, quad = (cg0 >> 3) & 3, e0 = cg0 & 7;
    int mth = row_e >> 4;
    int laneh = quad * 16 + (row_e & 15);
    hstore_base = (((size_t)(g * 4 + mth) * 32 + ksh) * 64 + laneh) * 8 + e0;
  }

  const short8* Afrag = (const short8*)smem;
  const int myflag = g * 64 + lane;

  // ---- persistent W_ih B-frags + bias for this wave's gate tile nt ----
  const int nt = w * 64 + s;                 // global ntile 0..255
  short8 Bih[13];
  {
    const short8* bsrc = wih + ((size_t)nt * 13) * 64 + lane;
#pragma unroll
    for (int ks = 0; ks < 13; ++ks) Bih[ks] = bsrc[ks * 64];
  }
  const float bv = bias[nt * 16 + (lane & 15)];

  // ---- prologue: stage xb(step 0) through LDS, compute xacc(0) ----
  f32x4 xacc[4];
  {
    // wave w copies mtile (g*4+w)'s 13 KB into A-region bytes [w*13K, ..)
    const short8* gsrc = xb + (((size_t)0 * 16 + g * 4 + w) * 13) * 64 + lane;
    char* ldst = smem + (size_t)w * 13 * 1024;
#pragma unroll
    for (int p = 0; p < 13; ++p)
      gld_lds16(gsrc + (size_t)p * 64, ldst + p * 1024);
    __syncthreads();   // P1: xb resident in LDS
#pragma unroll
    for (int a = 0; a < 4; ++a) { f32x4 v = {bv, bv, bv, bv}; xacc[a] = v; }
#pragma unroll
    for (int kk = 0; kk < 13; ++kk)
#pragma unroll
      for (int a = 0; a < 4; ++a)
        xacc[a] = MFMA_BF16(Afrag[(a * 13 + kk) * 64 + lane], Bih[kk], xacc[a]);
    __syncthreads();   // P2: all waves done reading xb before A-staging
  }

#pragma unroll 1
  for (int ts = 0; ts < 256; ++ts) {
    const uint16_t* hin = (ts & 1) ? hbuf1 : hbuf0;
    uint16_t* hout = (ts & 1) ? hbuf0 : hbuf1;

    // ---- stage this step's A h-tile into LDS: 128 x (1 KB), 32 per wave ----
    {
      const uint16_t* gbase = hin + (size_t)g * 65536
                              + (size_t)(w * 32) * 512 + (size_t)lane * 8;
      char* lbase = smem + (size_t)(w * 32) * 1024;
#pragma unroll
      for (int p = 0; p < 32; ++p)
        gld_lds16_coh(gbase + (size_t)p * 512, lbase + p * 1024);
    }

    // acc init from the in-register pipelined xg (f32, no bf16 round-trip)
    f32x4 acc[4];
#pragma unroll
    for (int a = 0; a < 4; ++a) acc[a] = xacc[a];

    __syncthreads();   // S1: vmcnt(0) drain — async LDS writes are NOT
                       // auto-ordered before ds_read (R6 NaN lesson)

    // ---- K loop: one W L2 stream, 4 A ds_reads, 4 MFMA per ks ----
#pragma unroll
    for (int ks = 0; ks < 32; ++ks) {
      short8 W = wstream[ks * 64];
      short8 A0 = Afrag[(0 * 32 + ks) * 64 + lane];
      short8 A1 = Afrag[(1 * 32 + ks) * 64 + lane];
      short8 A2 = Afrag[(2 * 32 + ks) * 64 + lane];
      short8 A3 = Afrag[(3 * 32 + ks) * 64 + lane];
      acc[0] = MFMA_BF16(A0, W, acc[0]);
      acc[1] = MFMA_BF16(A1, W, acc[1]);
      acc[2] = MFMA_BF16(A2, W, acc[2]);
      acc[3] = MFMA_BF16(A3, W, acc[3]);
    }

    // gates -> LDS  (C layout: col=lane&15, row=(lane>>4)*4+reg)
    {
      int r0 = (lane >> 4) * 4;
      int cc = lane & 15;
      int colc = w * 16 + cc;
#pragma unroll
      for (int a = 0; a < 4; ++a)
#pragma unroll
        for (int r = 0; r < 4; ++r)
          gl[(a * 16 + r0 + r) * 68 + colc] = acc[a][r];
    }
    __syncthreads();   // S3: gates visible (A-tile reads also complete)

    // ---- xb slice of step ts+1 -> A-region[0,52K) (async, zero VGPR) ----
    if (ts < 255) {
      const short8* gsrc =
          xb + (((size_t)(ts + 1) * 16 + g * 4 + w) * 13) * 64 + lane;
      char* ldst = smem + (size_t)w * 13 * 1024;
#pragma unroll
      for (int p = 0; p < 13; ++p)
        gld_lds16(gsrc + (size_t)p * 64, ldst + p * 1024);
    }

    // LSTM elementwise (PyTorch gate order i,f,g,o)
    float hv[4];
#pragma unroll
    for (int u = 0; u < 4; ++u) {
      int cj = j_e + u;
      float xi = gl[row_e * 68 + cj];
      float xf = gl[row_e * 68 + 16 + cj];
      float xg_ = gl[row_e * 68 + 32 + cj];
      float xo = gl[row_e * 68 + 48 + cj];
      float cn = sigm(xf) * c4[u] + sigm(xi) * tanh_f(xg_);
      c4[u] = cn;
      hv[u] = sigm(xo) * tanh_f(cn);
    }
    // h' as ONE contiguous 8-byte agent-scope store per thread
    {
      uint32_t w0 = (uint32_t)f2bf(hv[0]) | ((uint32_t)f2bf(hv[1]) << 16);
      uint32_t w1 = (uint32_t)f2bf(hv[2]) | ((uint32_t)f2bf(hv[3]) << 16);
      unsigned long long v = ((unsigned long long)w1 << 32) | w0;
      __hip_atomic_store((unsigned long long*)(hout + hstore_base), v,
                         __ATOMIC_RELAXED, __HIP_MEMORY_SCOPE_AGENT);
    }
    if (ts == 255) {
      f32x4 hh = {hv[0], hv[1], hv[2], hv[3]};
      *(f32x4*)(h_final + (size_t)R_e * 1024 + col_e) = hh;
    } else {
      // ---- group-local barrier (64 blocks of group g), fence-free ----
      __syncthreads();   // S4: drains every wave's h' stores AND xb stage
      if (tid == 0) {
        __hip_atomic_store(&flags[bid], (uint32_t)(ts + 1),
                           __ATOMIC_RELAXED, __HIP_MEMORY_SCOPE_AGENT);
      }
      // xg-MFMA for step ts+1 from LDS-staged xb: 52 ds_read_b128 + 52 MFMA
      // per wave, entirely inside the previously-idle poll window.
#pragma unroll
      for (int a = 0; a < 4; ++a) { f32x4 v = {bv, bv, bv, bv}; xacc[a] = v; }
#pragma unroll
      for (int kk = 0; kk < 13; ++kk)
#pragma unroll
        for (int a = 0; a < 4; ++a)
          xacc[a] =
              MFMA_BF16(Afrag[(a * 13 + kk) * 64 + lane], Bih[kk], xacc[a]);
      __syncthreads();   // S5: all xb reads complete before any wave's next
                         // A-staging overwrites the region
      // all lanes poll one peer flag each; wave proceeds when all 64 peers
      // released. gl(l+1) writes are fenced by S1(l+1).
      while (__hip_atomic_load(&flags[myflag], __ATOMIC_RELAXED,
                               __HIP_MEMORY_SCOPE_AGENT) < (uint32_t)(ts + 1)) {
        __builtin_amdgcn_s_sleep(1);
      }
    }
  }
}

// ---------------------------------------------------------------------------
// MLP layer 1: hidden = relu(h_last @ W1^T + b1), fp32 VALU.
// ---------------------------------------------------------------------------
__global__ __launch_bounds__(256) void mlp1_kernel(
    const float* __restrict__ h_final, const float* __restrict__ W1,
    const float* __restrict__ b1, float* __restrict__ hidden)
{
  __shared__ float hl[8 * 1024];       // 32 KB
  __shared__ float part[4 * 64 * 8];   // 8 KB
  int tid = threadIdx.x;
  int rb = blockIdx.x;                 // 0..31
  int cb = blockIdx.y;                 // 0..7
  const f32x4* hsrc = (const f32x4*)(h_final + (size_t)rb * 8 * 1024);
  for (int i = tid; i < 2048; i += 256) ((f32x4*)hl)[i] = hsrc[i];
  __syncthreads();
  int cell_l = tid & 63;
  int kq = tid >> 6;                   // k quarter
  int cell = cb * 64 + cell_l;
  float accv[8] = {0,0,0,0,0,0,0,0};
  const f32x4* wrow = (const f32x4*)(W1 + (size_t)cell * 1024) + kq * 64;
  const f32x4* hl4 = (const f32x4*)hl;
  for (int k4 = 0; k4 < 64; ++k4) {
    f32x4 wv = wrow[k4];
    int kidx = kq * 64 + k4;
#pragma unroll
    for (int r = 0; r < 8; ++r) {
      f32x4 hv = hl4[r * 256 + kidx];
      accv[r] += wv[0] * hv[0] + wv[1] * hv[1] + wv[2] * hv[2] + wv[3] * hv[3];
    }
  }
#pragma unroll
  for (int r = 0; r < 8; ++r) part[(kq * 64 + cell_l) * 8 + r] = accv[r];
  __syncthreads();
#pragma unroll
  for (int rr = 0; rr < 2; ++rr) {
    int r = kq * 2 + rr;
    float sum = b1[cell];
    for (int q = 0; q < 4; ++q) sum += part[(q * 64 + cell_l) * 8 + r];
    hidden[(size_t)(rb * 8 + r) * 512 + cell] = fmaxf(sum, 0.0f);
  }
}

// MLP layer 2: out[b] = hidden[b] . W2 + b2
__global__ __launch_bounds__(256) void mlp2_kernel(
    const float* __restrict__ hidden, const float* __restrict__ W2,
    const float* __restrict__ b2, float* __restrict__ out)
{
  __shared__ float w2l[512];
  int tid = threadIdx.x;
  for (int i = tid; i < 512; i += 256) w2l[i] = W2[i];
  __syncthreads();
  const f32x4* hrow = (const f32x4*)(hidden + (size_t)tid * 512);
  const f32x4* w4 = (const f32x4*)w2l;
  float acc = b2[0];
  for (int k = 0; k < 128; ++k) {
    f32x4 a = hrow[k], b = w4[k];
    acc += a[0] * b[0] + a[1] * b[1] + a[2] * b[2] + a[3] * b[3];
  }
  out[tid] = acc;
}

// ---------------------------------------------------------------------------
extern "C" void kernel_launch(void* const* d_in, const int* in_sizes, int n_in,
                              void* d_out, int out_size, void* d_ws, size_t ws_size,
                              hipStream_t stream)
{
  (void)in_sizes; (void)n_in; (void)out_size;
  if (ws_size < WS_NEED) return;   // workspace too small -> loud bench failure

  const float* xt   = (const float*)d_in[0];
  const float* xa   = (const float*)d_in[1];
  const float* xv   = (const float*)d_in[2];
  const float* W_ih = (const float*)d_in[3];
  const float* W_hh = (const float*)d_in[4];
  const float* b_ih = (const float*)d_in[5];
  const float* b_hh = (const float*)d_in[6];
  const float* W1   = (const float*)d_in[7];
  const float* b1   = (const float*)d_in[8];
  const float* W2   = (const float*)d_in[9];
  const float* b2   = (const float*)d_in[10];
  float* out = (float*)d_out;
  char* ws = (char*)d_ws;

  uint32_t* flags   = (uint32_t*)(ws + OFF_FLAGS);
  uint16_t* hb0     = (uint16_t*)(ws + OFF_HBUF0);
  uint16_t* hb1     = (uint16_t*)(ws + OFF_HBUF1);
  float*    h_final = (float*)(ws + OFF_HFIN);
  float*    hidden  = (float*)(ws + OFF_HID);
  float*    bias    = (float*)(ws + OFF_BIAS);
  uint16_t* whh_p   = (uint16_t*)(ws + OFF_WHH);
  uint16_t* wih_p   = (uint16_t*)(ws + OFF_WIH);
  uint16_t* xb      = (uint16_t*)(ws + OFF_XB);

  // allow >64KB dynamic LDS for the scan kernel (idempotent, capture-safe)
  hipFuncSetAttribute((const void*)scan_kernel,
                      hipFuncAttributeMaxDynamicSharedMemorySize, 148480);

  // zero flags + h state (ws is poisoned before every launch)
  hipMemsetAsync(ws, 0, ZERO_SPAN, stream);

  pack_xb_kernel  <<<13312, 256, 0, stream>>>(xt, xa, xv, xb);
  pack_whh_kernel <<<2048,  256, 0, stream>>>(W_hh, whh_p);
  pack_wih_kernel <<<832,   256, 0, stream>>>(W_ih, wih_p);
  pack_bias_kernel<<<16,    256, 0, stream>>>(b_ih, b_hh, bias);

  scan_kernel<<<256, 256, 148480, stream>>>(
      whh_p, (const short8*)xb, (const short8*)wih_p, bias,
      hb0, hb1, h_final, flags);

  mlp1_kernel<<<dim3(32, 8), 256, 0, stream>>>(h_final, W1, b1, hidden);
  mlp2_kernel<<<1, 256, 0, stream>>>(hidden, W2, b2, out);
}

// Round 6
// 1850.828 us; speedup vs baseline: 2.4302x; 1.0321x over previous
//
#include <hip/hip_runtime.h>
#include <cstdint>
#include <cstddef>

// ============================================================================
// EFLSTM: concat(x_text,x_audio,x_vision) -> LSTM(H=1024, T=256, B=256) -> MLP
//
// Round 14 = R13 (proven: 1787us scan, 1910 total) with G=8 geometry:
// 8 batch-groups x 32 hidden-slice blocks (was 4 x 64).
//  - R13 analysis: step 6.98us = h-broadcast staging (each of 64 blocks/group
//    reads the SAME 128 KB tile from LLC -> 32 MB/step, ~2.5us serialized)
//    + 4x-redundant A LDS reads (512 KB/CU/step) + sync.
//  - R14: block = (g,s2) owns 32 batch rows x 32 hidden cols. Wave q = gate
//    quadrant computes 2 mtiles x 2 ntiles with A-register-reuse:
//      * h-broadcast halves: 64 KB/block, 16 MB/step LLC
//      * A LDS reads halve: 64 KB/wave, 256 KB/CU
//      * W_hh L2 doubles (2 streams/wave) but stays XCD-L2-resident
//        (same-s2 blocks are 32 apart -> same XCD under round-robin; 1 MB/XCD)
//  - Identical FP math (same K order/tiles) -> absmax unchanged.
//  - Step protocol byte-identical: S1 (post-A-stage vmcnt drain), S3 (gates),
//    xb stage (async into dead A region), S4 (h' + xb drain), flag release,
//    xg-MFMA in poll window, S5 (xb-read fence), 32-peer poll.
// LDS: A 64 KB + gl [32][132] 16.9 KB = 82432 B. 1 block/CU.
// ============================================================================

typedef __attribute__((ext_vector_type(8))) short short8;   // 8 x bf16
typedef __attribute__((ext_vector_type(4))) float f32x4;

#define MFMA_BF16(A,B,C) __builtin_amdgcn_mfma_f32_16x16x32_bf16((A),(B),(C),0,0,0)

// ---- workspace layout (bytes) ----
#define OFF_FLAGS 0u            // 256 * 4 (padded to 4096)
#define OFF_HBUF0 4096u         // 256*1024*2 = 524288   (A-frag-linear bf16)
#define ZERO_SPAN 528384u       // flags + hbuf0 zeroed every launch
#define OFF_HBUF1 528384u       // 524288
#define OFF_HFIN  1052672u      // 256*1024*4 = 1048576  (fp32 h_last)
#define OFF_HID   2101248u      // 256*512*4  = 524288   (fp32 mlp hidden)
#define OFF_BIAS  2625536u      // 4096*4 (padded to 16384)
#define OFF_WHH   2641920u      // 64 slices * 64*1024 * 2 = 8388608
#define OFF_WIH   11030528u     // 256*13*64*8*2 = 3407872
#define OFF_XB    14438400u     // 4096*13*64*8*2 = 54525952
#define WS_NEED   68964352ull

static __device__ __forceinline__ uint16_t f2bf(float f) {
  uint32_t u = __builtin_bit_cast(uint32_t, f);
  uint32_t r = u + 0x7FFFu + ((u >> 16) & 1u);   // round-nearest-even
  return (uint16_t)(r >> 16);
}
static __device__ __forceinline__ float sigm(float x) {
  return 1.0f / (1.0f + __expf(-x));
}
static __device__ __forceinline__ float tanh_f(float x) {
  float e = __expf(2.0f * x);
  return 1.0f - 2.0f / (e + 1.0f);
}
// async global->LDS, 16B/lane, aux=0x11 (SC0|SC1): IF-coherent read,
// bypasses the non-coherent per-XCD L2.
static __device__ __forceinline__ void gld_lds16_coh(const void* gsrc, void* ldst) {
  __builtin_amdgcn_global_load_lds(
      (const __attribute__((address_space(1))) uint32_t*)gsrc,
      (__attribute__((address_space(3))) uint32_t*)ldst, 16, 0, 0x11);
}
// async global->LDS, 16B/lane, aux=0 (normal cached read: xb is read-only,
// producer finished before scan launch -> no coherence needed, L2 may serve)
static __device__ __forceinline__ void gld_lds16(const void* gsrc, void* ldst) {
  __builtin_amdgcn_global_load_lds(
      (const __attribute__((address_space(1))) uint32_t*)gsrc,
      (__attribute__((address_space(3))) uint32_t*)ldst, 16, 0, 0);
}

// ---------------------------------------------------------------------------
// pack x (3 tensors, fp32 [B,T,D_i]) -> xb bf16 A-frag-linear:
//   [mtile 4096][ks 13][lane 64][8], m = t*256+b, k padded to 416 with zeros
// ---------------------------------------------------------------------------
__global__ __launch_bounds__(256) void pack_xb_kernel(
    const float* __restrict__ xt, const float* __restrict__ xa,
    const float* __restrict__ xv, uint16_t* __restrict__ xb)
{
  int id = blockIdx.x * 256 + threadIdx.x;          // < 4096*13*64 = 3407872
  int lane = id & 63;
  int rem  = id >> 6;
  int ks = rem % 13;
  int mt = rem / 13;
  int m = mt * 16 + (lane & 15);
  int t = m >> 8;
  int b = m & 255;
  int k0 = ks * 32 + (lane >> 4) * 8;
  size_t base = (size_t)b * 256 + t;
  uint16_t vals[8];
#pragma unroll
  for (int e = 0; e < 8; ++e) {
    int k = k0 + e;
    float v;
    if (k < 300)      v = xt[base * 300 + k];
    else if (k < 374) v = xa[base * 74  + (k - 300)];
    else if (k < 409) v = xv[base * 35  + (k - 374)];
    else              v = 0.0f;
    vals[e] = f2bf(v);
  }
  uint32_t* d32 = (uint32_t*)(xb + (size_t)id * 8);
#pragma unroll
  for (int i = 0; i < 4; ++i)
    d32[i] = (uint32_t)vals[2*i] | ((uint32_t)vals[2*i+1] << 16);
}

// ---------------------------------------------------------------------------
// pack W_hh fp32 [4096,1024] -> bf16 B-frag-linear per slice s (of 64):
//   [s 64][q 4][ks 32][lane 64][8], row = q*1024 + 16*s + (lane&15)
// ---------------------------------------------------------------------------
__global__ __launch_bounds__(256) void pack_whh_kernel(
    const float* __restrict__ whh, uint16_t* __restrict__ wp)
{
  int id = blockIdx.x * 256 + threadIdx.x;          // < 64*4*32*64 = 524288
  int lane = id & 63;
  int ks = (id >> 6) & 31;
  int q  = (id >> 11) & 3;
  int s  = id >> 13;
  int row = q * 1024 + s * 16 + (lane & 15);
  int k0 = ks * 32 + (lane >> 4) * 8;
  const float* src = whh + (size_t)row * 1024 + k0;
  uint16_t vals[8];
#pragma unroll
  for (int e = 0; e < 8; ++e) vals[e] = f2bf(src[e]);
  uint32_t* d32 = (uint32_t*)(wp + (size_t)id * 8);
#pragma unroll
  for (int i = 0; i < 4; ++i)
    d32[i] = (uint32_t)vals[2*i] | ((uint32_t)vals[2*i+1] << 16);
}

// ---------------------------------------------------------------------------
// pack W_ih fp32 [4096,409] -> bf16 B-frag-linear [nt 256][ks 13][lane][8]
// ---------------------------------------------------------------------------
__global__ __launch_bounds__(256) void pack_wih_kernel(
    const float* __restrict__ wih, uint16_t* __restrict__ wp)
{
  int id = blockIdx.x * 256 + threadIdx.x;          // < 256*13*64 = 212992
  int lane = id & 63;
  int rem = id >> 6;
  int ks = rem % 13;
  int nt = rem / 13;
  int n = nt * 16 + (lane & 15);
  int k0 = ks * 32 + (lane >> 4) * 8;
  uint16_t vals[8];
#pragma unroll
  for (int e = 0; e < 8; ++e) {
    int k = k0 + e;
    vals[e] = (k < 409) ? f2bf(wih[(size_t)n * 409 + k]) : (uint16_t)0;
  }
  uint32_t* d32 = (uint32_t*)(wp + (size_t)id * 8);
#pragma unroll
  for (int i = 0; i < 4; ++i)
    d32[i] = (uint32_t)vals[2*i] | ((uint32_t)vals[2*i+1] << 16);
}

__global__ __launch_bounds__(256) void pack_bias_kernel(
    const float* __restrict__ b_ih, const float* __restrict__ b_hh,
    float* __restrict__ bias)
{
  int id = blockIdx.x * 256 + threadIdx.x;          // < 4096
  bias[id] = b_ih[id] + b_hh[id];
}

// ---------------------------------------------------------------------------
// Persistent scan, G=8: 256 blocks x 256 threads, 1 block/CU, ONE launch.
// group g = bid>>5 owns batch rows [32g,32g+32); s2 = bid&31 owns hidden
// cols [32*s2, 32*s2+32) (old slices 2*s2, 2*s2+1). Wave q = gate quadrant,
// computes 2 mtiles x 2 ntiles with A-register reuse.
// ---------------------------------------------------------------------------
__global__ __launch_bounds__(256, 1) void scan_kernel(
    const uint16_t* __restrict__ whh_p, const short8* __restrict__ xb,
    const short8* __restrict__ wih, const float* __restrict__ bias,
    uint16_t* __restrict__ hbuf0, uint16_t* __restrict__ hbuf1,
    float* __restrict__ h_final, uint32_t* flags)
{
  extern __shared__ char smem[];
  // smem[0     .. 65536): A tile, 2 mtiles x 32 ks x 64 lanes x 16 B
  //                       (doubles as xb staging [0,26624) in wait window)
  // smem[65536 .. 82432): gate exchange, [32][132] fp32
  float* gl = (float*)(smem + 65536);

  const int tid = threadIdx.x;
  const int bid = blockIdx.x;
  const int g = bid >> 5, s2 = bid & 31;
  const int lane = tid & 63, q = tid >> 6;   // q = gate quadrant

  // two wave-private W_hh streams (old slices 2*s2 and 2*s2+1, quadrant q)
  const short8* ws0 = (const short8*)whh_p
                      + (size_t)(s2 * 2 + 0) * 8192 + (size_t)q * 2048 + lane;
  const short8* ws1 = (const short8*)whh_p
                      + (size_t)(s2 * 2 + 1) * 8192 + (size_t)q * 2048 + lane;

  // elementwise ownership: thread handles units col_e..col_e+3 of row R_e
  const int row_e = tid >> 3;                // 0..31
  const int j_e = (tid & 7) * 4;             // 0,4,...,28
  const int R_e = g * 32 + row_e;
  const int col_e = s2 * 32 + j_e;           // hidden col base
  f32x4 c4 = {0.0f, 0.0f, 0.0f, 0.0f};      // cell state lives in regs

  // precompute h'-store address (4 consecutive bf16 = one aligned 8B store)
  size_t hstore_base;
  {
    int cg0 = col_e;
    int ksh = cg0 >> 5, quad = (cg0 >> 3) & 3, e0 = cg0 & 7;
    int mth = row_e >> 4;                    // 0..1
    int laneh = quad * 16 + (row_e & 15);
    hstore_base = (((size_t)(g * 2 + mth) * 32 + ksh) * 64 + laneh) * 8 + e0;
  }

  const short8* Afrag = (const short8*)smem;
  const int myflag = g * 32 + (lane & 31);   // 32 peers, each polled twice

  // ---- persistent W_ih B-frags + bias for this wave's 2 gate ntiles ----
  short8 Bih0[13], Bih1[13];
  {
    const short8* b0 = wih + ((size_t)(q * 64 + s2 * 2 + 0) * 13) * 64 + lane;
    const short8* b1 = wih + ((size_t)(q * 64 + s2 * 2 + 1) * 13) * 64 + lane;
#pragma unroll
    for (int ks = 0; ks < 13; ++ks) { Bih0[ks] = b0[ks * 64]; Bih1[ks] = b1[ks * 64]; }
  }
  const float bv0 = bias[q * 1024 + (s2 * 2 + 0) * 16 + (lane & 15)];
  const float bv1 = bias[q * 1024 + (s2 * 2 + 1) * 16 + (lane & 15)];

  // ---- prologue: stage xb(step 0) through LDS, compute xacc(0) ----
  f32x4 xacc00, xacc01, xacc10, xacc11;
  {
    if (q < 2) {   // wave q stages mtile g*2+q's 13 KB into [q*13K, ..)
      const short8* gsrc = xb + ((size_t)(g * 2 + q)) * 832 + lane;
      char* ldst = smem + (size_t)q * 13312;
#pragma unroll
      for (int p = 0; p < 13; ++p)
        gld_lds16(gsrc + (size_t)p * 64, ldst + p * 1024);
    }
    __syncthreads();   // P1: xb resident in LDS (vmcnt drained)
    f32x4 v0 = {bv0, bv0, bv0, bv0}, v1 = {bv1, bv1, bv1, bv1};
    xacc00 = v0; xacc01 = v1; xacc10 = v0; xacc11 = v1;
#pragma unroll
    for (int kk = 0; kk < 13; ++kk) {
      short8 A0 = Afrag[kk * 64 + lane];
      short8 A1 = Afrag[832 + kk * 64 + lane];
      xacc00 = MFMA_BF16(A0, Bih0[kk], xacc00);
      xacc01 = MFMA_BF16(A0, Bih1[kk], xacc01);
      xacc10 = MFMA_BF16(A1, Bih0[kk], xacc10);
      xacc11 = MFMA_BF16(A1, Bih1[kk], xacc11);
    }
    __syncthreads();   // P2: all waves done reading xb before A-staging
  }

#pragma unroll 1
  for (int ts = 0; ts < 256; ++ts) {
    const uint16_t* hin = (ts & 1) ? hbuf1 : hbuf0;
    uint16_t* hout = (ts & 1) ? hbuf0 : hbuf1;

    // ---- stage this step's A h-tile into LDS: 64 x (1 KB), 16 per wave ----
    {
      const uint16_t* gbase = hin + (size_t)g * 32768
                              + (size_t)q * 8192 + (size_t)lane * 8;
      char* lbase = smem + (size_t)q * 16384;
#pragma unroll
      for (int p = 0; p < 16; ++p)
        gld_lds16_coh(gbase + (size_t)p * 512, lbase + p * 1024);
    }

    // acc init from the in-register pipelined xg (f32, no bf16 round-trip)
    f32x4 acc00 = xacc00, acc01 = xacc01, acc10 = xacc10, acc11 = xacc11;

    __syncthreads();   // S1: vmcnt(0) drain — async LDS writes are NOT
                       // auto-ordered before ds_read (R6 NaN lesson)

    // ---- K loop: two W L2 streams, 2 A ds_reads, 4 MFMA per ks ----
#pragma unroll
    for (int ks = 0; ks < 32; ++ks) {
      short8 W0 = ws0[ks * 64];
      short8 W1 = ws1[ks * 64];
      short8 A0 = Afrag[(0 * 32 + ks) * 64 + lane];
      short8 A1 = Afrag[(1 * 32 + ks) * 64 + lane];
      acc00 = MFMA_BF16(A0, W0, acc00);
      acc01 = MFMA_BF16(A0, W1, acc01);
      acc10 = MFMA_BF16(A1, W0, acc10);
      acc11 = MFMA_BF16(A1, W1, acc11);
    }

    // gates -> LDS  (C layout: col=lane&15, row=(lane>>4)*4+reg)
    {
      int r0 = (lane >> 4) * 4;
      int cc = lane & 15;
#pragma unroll
      for (int r = 0; r < 4; ++r) {
        gl[(0 * 16 + r0 + r) * 132 + q * 32 +  0 + cc] = acc00[r];
        gl[(0 * 16 + r0 + r) * 132 + q * 32 + 16 + cc] = acc01[r];
        gl[(1 * 16 + r0 + r) * 132 + q * 32 +  0 + cc] = acc10[r];
        gl[(1 * 16 + r0 + r) * 132 + q * 32 + 16 + cc] = acc11[r];
      }
    }
    __syncthreads();   // S3: gates visible (A-tile reads also complete)

    // ---- xb slice of step ts+1 -> A-region[0,26624) (async, zero VGPR) ----
    if (ts < 255 && q < 2) {
      const short8* gsrc =
          xb + ((size_t)(ts + 1) * 16 + g * 2 + q) * 832 + lane;
      char* ldst = smem + (size_t)q * 13312;
#pragma unroll
      for (int p = 0; p < 13; ++p)
        gld_lds16(gsrc + (size_t)p * 64, ldst + p * 1024);
    }

    // LSTM elementwise (PyTorch gate order i,f,g,o; gl cols: gate*32 + c)
    float hv[4];
#pragma unroll
    for (int u = 0; u < 4; ++u) {
      int c = j_e + u;
      float xi  = gl[row_e * 132 +  0 + c];
      float xf  = gl[row_e * 132 + 32 + c];
      float xg_ = gl[row_e * 132 + 64 + c];
      float xo  = gl[row_e * 132 + 96 + c];
      float cn = sigm(xf) * c4[u] + sigm(xi) * tanh_f(xg_);
      c4[u] = cn;
      hv[u] = sigm(xo) * tanh_f(cn);
    }
    // h' as ONE contiguous 8-byte agent-scope store per thread
    {
      uint32_t w0 = (uint32_t)f2bf(hv[0]) | ((uint32_t)f2bf(hv[1]) << 16);
      uint32_t w1 = (uint32_t)f2bf(hv[2]) | ((uint32_t)f2bf(hv[3]) << 16);
      unsigned long long v = ((unsigned long long)w1 << 32) | w0;
      __hip_atomic_store((unsigned long long*)(hout + hstore_base), v,
                         __ATOMIC_RELAXED, __HIP_MEMORY_SCOPE_AGENT);
    }
    if (ts == 255) {
      f32x4 hh = {hv[0], hv[1], hv[2], hv[3]};
      *(f32x4*)(h_final + (size_t)R_e * 1024 + col_e) = hh;
    } else {
      // ---- group-local barrier (32 blocks of group g), fence-free ----
      __syncthreads();   // S4: drains every wave's h' stores AND xb stage
      if (tid == 0) {
        __hip_atomic_store(&flags[bid], (uint32_t)(ts + 1),
                           __ATOMIC_RELAXED, __HIP_MEMORY_SCOPE_AGENT);
      }
      // xg-MFMA for step ts+1 from LDS-staged xb: 26 ds_read_b128 + 52 MFMA
      // per wave, entirely inside the previously-idle poll window.
      {
        f32x4 v0 = {bv0, bv0, bv0, bv0}, v1 = {bv1, bv1, bv1, bv1};
        xacc00 = v0; xacc01 = v1; xacc10 = v0; xacc11 = v1;
#pragma unroll
        for (int kk = 0; kk < 13; ++kk) {
          short8 A0 = Afrag[kk * 64 + lane];
          short8 A1 = Afrag[832 + kk * 64 + lane];
          xacc00 = MFMA_BF16(A0, Bih0[kk], xacc00);
          xacc01 = MFMA_BF16(A0, Bih1[kk], xacc01);
          xacc10 = MFMA_BF16(A1, Bih0[kk], xacc10);
          xacc11 = MFMA_BF16(A1, Bih1[kk], xacc11);
        }
      }
      __syncthreads();   // S5: all xb reads complete before any wave's next
                         // A-staging overwrites the region
      // all lanes poll peer flags; wave proceeds when all 32 peers released.
      while (__hip_atomic_load(&flags[myflag], __ATOMIC_RELAXED,
                               __HIP_MEMORY_SCOPE_AGENT) < (uint32_t)(ts + 1)) {
        __builtin_amdgcn_s_sleep(1);
      }
    }
  }
}

// ---------------------------------------------------------------------------
// MLP layer 1: hidden = relu(h_last @ W1^T + b1), fp32 VALU.
// ---------------------------------------------------------------------------
__global__ __launch_bounds__(256) void mlp1_kernel(
    const float* __restrict__ h_final, const float* __restrict__ W1,
    const float* __restrict__ b1, float* __restrict__ hidden)
{
  __shared__ float hl[8 * 1024];       // 32 KB
  __shared__ float part[4 * 64 * 8];   // 8 KB
  int tid = threadIdx.x;
  int rb = blockIdx.x;                 // 0..31
  int cb = blockIdx.y;                 // 0..7
  const f32x4* hsrc = (const f32x4*)(h_final + (size_t)rb * 8 * 1024);
  for (int i = tid; i < 2048; i += 256) ((f32x4*)hl)[i] = hsrc[i];
  __syncthreads();
  int cell_l = tid & 63;
  int kq = tid >> 6;                   // k quarter
  int cell = cb * 64 + cell_l;
  float accv[8] = {0,0,0,0,0,0,0,0};
  const f32x4* wrow = (const f32x4*)(W1 + (size_t)cell * 1024) + kq * 64;
  const f32x4* hl4 = (const f32x4*)hl;
  for (int k4 = 0; k4 < 64; ++k4) {
    f32x4 wv = wrow[k4];
    int kidx = kq * 64 + k4;
#pragma unroll
    for (int r = 0; r < 8; ++r) {
      f32x4 hv = hl4[r * 256 + kidx];
      accv[r] += wv[0] * hv[0] + wv[1] * hv[1] + wv[2] * hv[2] + wv[3] * hv[3];
    }
  }
#pragma unroll
  for (int r = 0; r < 8; ++r) part[(kq * 64 + cell_l) * 8 + r] = accv[r];
  __syncthreads();
#pragma unroll
  for (int rr = 0; rr < 2; ++rr) {
    int r = kq * 2 + rr;
    float sum = b1[cell];
    for (int q = 0; q < 4; ++q) sum += part[(q * 64 + cell_l) * 8 + r];
    hidden[(size_t)(rb * 8 + r) * 512 + cell] = fmaxf(sum, 0.0f);
  }
}

// MLP layer 2: out[b] = hidden[b] . W2 + b2
__global__ __launch_bounds__(256) void mlp2_kernel(
    const float* __restrict__ hidden, const float* __restrict__ W2,
    const float* __restrict__ b2, float* __restrict__ out)
{
  __shared__ float w2l[512];
  int tid = threadIdx.x;
  for (int i = tid; i < 512; i += 256) w2l[i] = W2[i];
  __syncthreads();
  const f32x4* hrow = (const f32x4*)(hidden + (size_t)tid * 512);
  const f32x4* w4 = (const f32x4*)w2l;
  float acc = b2[0];
  for (int k = 0; k < 128; ++k) {
    f32x4 a = hrow[k], b = w4[k];
    acc += a[0] * b[0] + a[1] * b[1] + a[2] * b[2] + a[3] * b[3];
  }
  out[tid] = acc;
}

// ---------------------------------------------------------------------------
extern "C" void kernel_launch(void* const* d_in, const int* in_sizes, int n_in,
                              void* d_out, int out_size, void* d_ws, size_t ws_size,
                              hipStream_t stream)
{
  (void)in_sizes; (void)n_in; (void)out_size;
  if (ws_size < WS_NEED) return;   // workspace too small -> loud bench failure

  const float* xt   = (const float*)d_in[0];
  const float* xa   = (const float*)d_in[1];
  const float* xv   = (const float*)d_in[2];
  const float* W_ih = (const float*)d_in[3];
  const float* W_hh = (const float*)d_in[4];
  const float* b_ih = (const float*)d_in[5];
  const float* b_hh = (const float*)d_in[6];
  const float* W1   = (const float*)d_in[7];
  const float* b1   = (const float*)d_in[8];
  const float* W2   = (const float*)d_in[9];
  const float* b2   = (const float*)d_in[10];
  float* out = (float*)d_out;
  char* ws = (char*)d_ws;

  uint32_t* flags   = (uint32_t*)(ws + OFF_FLAGS);
  uint16_t* hb0     = (uint16_t*)(ws + OFF_HBUF0);
  uint16_t* hb1     = (uint16_t*)(ws + OFF_HBUF1);
  float*    h_final = (float*)(ws + OFF_HFIN);
  float*    hidden  = (float*)(ws + OFF_HID);
  float*    bias    = (float*)(ws + OFF_BIAS);
  uint16_t* whh_p   = (uint16_t*)(ws + OFF_WHH);
  uint16_t* wih_p   = (uint16_t*)(ws + OFF_WIH);
  uint16_t* xb      = (uint16_t*)(ws + OFF_XB);

  // allow >64KB dynamic LDS for the scan kernel (idempotent, capture-safe)
  hipFuncSetAttribute((const void*)scan_kernel,
                      hipFuncAttributeMaxDynamicSharedMemorySize, 82432);

  // zero flags + h state (ws is poisoned before every launch)
  hipMemsetAsync(ws, 0, ZERO_SPAN, stream);

  pack_xb_kernel  <<<13312, 256, 0, stream>>>(xt, xa, xv, xb);
  pack_whh_kernel <<<2048,  256, 0, stream>>>(W_hh, whh_p);
  pack_wih_kernel <<<832,   256, 0, stream>>>(W_ih, wih_p);
  pack_bias_kernel<<<16,    256, 0, stream>>>(b_ih, b_hh, bias);

  scan_kernel<<<256, 256, 82432, stream>>>(
      whh_p, (const short8*)xb, (const short8*)wih_p, bias,
      hb0, hb1, h_final, flags);

  mlp1_kernel<<<dim3(32, 8), 256, 0, stream>>>(h_final, W1, b1, hidden);
  mlp2_kernel<<<1, 256, 0, stream>>>(hidden, W2, b2, out);
}